// Round 5
// baseline (194.965 us; speedup 1.0000x reference)
//
#include <hip/hip_runtime.h>
#include <hip/hip_bf16.h>

#define KDIM 4096
#define NTILE 64                 // K-tiles of 64
#define NELEM16 (1u << 24)       // 4096*4096 elems per matrix

typedef float f32x4 __attribute__((ext_vector_type(4)));
typedef short bf16x8 __attribute__((ext_vector_type(8)));

typedef const __attribute__((address_space(1))) unsigned int g_u32;
typedef __attribute__((address_space(3))) unsigned int l_u32;

__device__ __forceinline__ void gload_lds16(const void* g, void* l) {
    __builtin_amdgcn_global_load_lds((g_u32*)g, (l_u32*)l, 16, 0, 0);
}

__device__ __forceinline__ unsigned int pack_bf16x2(float lo, float hi) {
    __hip_bfloat162 h = __float22bfloat162_rn(float2{lo, hi});
    union { __hip_bfloat162 h; unsigned int u; } c; c.h = h; return c.u;
}

// ---- pack fp32 [4096][4096] -> tiled + XOR-swizzled bf16 staging image ----
__global__ __launch_bounds__(256)
void pack_swz2(const float* __restrict__ x, const float* __restrict__ W,
               unsigned short* __restrict__ xb, unsigned short* __restrict__ wb)
{
    const unsigned int stride = gridDim.x * blockDim.x;
    for (unsigned int i = blockIdx.x * blockDim.x + threadIdx.x; i < (1u << 22); i += stride) {
        const unsigned int j  = i & ((1u << 21) - 1);
        const float* __restrict__ in = (i >> 21) ? W : x;
        unsigned short* __restrict__ out = (i >> 21) ? wb : xb;
        const unsigned int cp = j & 7;
        const unsigned int rl = (j >> 3) & 127;
        const unsigned int c  = cp ^ (rl & 7);
        const unsigned int h  = (j >> 10) & 1;
        const unsigned int kt = (j >> 11) & 63;
        const unsigned int rt = j >> 17;
        const unsigned int row = rt * 256 + h * 128 + rl;
        const unsigned int col = kt * 64 + c * 8;
        const float4* s = (const float4*)(in + (size_t)row * KDIM + col);
        const float4 a = s[0], b = s[1];
        uint4 o;
        o.x = pack_bf16x2(a.x, a.y); o.y = pack_bf16x2(a.z, a.w);
        o.z = pack_bf16x2(b.x, b.y); o.w = pack_bf16x2(b.z, b.w);
        *(uint4*)(out + (size_t)j * 8) = o;
    }
}

// ---- 256x256 8-phase GEMM with one-phase-ahead LDS reads ----
// LDS elem offsets: buf*32768 + op*16384 + half*8192 + rowfrag*1024 + c15*64 + swzchunk*8
#define STAGE(matBase, kt, h, bufp, opIdx)                                      \
    {                                                                           \
        const unsigned short* g_ = (matBase) + ((size_t)(kt) * 2 + (h)) * 8192; \
        const unsigned int lo_ = (bufp) * 32768 + (opIdx) * 16384 + (h) * 8192 + wid * 1024; \
        gload_lds16(g_ + stageOff,       &lds[lo_]);                            \
        gload_lds16(g_ + stageOff + 512, &lds[lo_ + 512]);                      \
    }

#define READ_A(dst, base)                                                       \
    _Pragma("unroll") for (int m = 0; m < 4; ++m)                               \
      _Pragma("unroll") for (int k = 0; k < 2; ++k)                             \
        dst[m][k] = *(const bf16x8*)&lds[(base) + (m * 2 + wm) * 1024 + rdBase + kcp[k]];

#define READ_B(dst, base)                                                       \
    _Pragma("unroll") for (int n = 0; n < 2; ++n)                               \
      _Pragma("unroll") for (int k = 0; k < 2; ++k)                             \
        dst[n][k] = *(const bf16x8*)&lds[(base) + (n * 4 + wn) * 1024 + rdBase + kcp[k]];

#define MFMA16(AF, BF, MO, NO)                                                  \
    __builtin_amdgcn_s_setprio(1);                                              \
    _Pragma("unroll") for (int m = 0; m < 4; ++m)                               \
      _Pragma("unroll") for (int n = 0; n < 2; ++n)                             \
        _Pragma("unroll") for (int k = 0; k < 2; ++k)                           \
          acc[(MO) + m][(NO) + n] = __builtin_amdgcn_mfma_f32_16x16x32_bf16(    \
              AF[m][k], BF[n][k], acc[(MO) + m][(NO) + n], 0, 0, 0);            \
    __builtin_amdgcn_s_setprio(0);

// Per tile T (buf parity PB/32768): quads P1:(A0,B0) P2:(A0,B1) P3:(A1,B1) P4:(A1,B0).
// Reads are ONE PHASE AHEAD: P1 reads B1(T) [for P2], P2 reads A1(T) [for P3],
// P3 reads A0(T+1) [for P1'], P4 reads B0(T+1) [for P1'] -> {4,8,8,4} balanced.
// lgkmcnt(n_i) drains all older reads (incl. this phase's operands + the region
// about to be overwritten by this phase's STAGE) while leaving the fresh reads in
// flight so their service overlaps this phase's MFMA cluster.
// Stages: P1:A0(T+2) P2:B0(T+2) P3:B1(T+2) P4:A1(T+2) (uniform t+2 guard).
// vmcnt(4) once per tile leaves exactly {B1(T+2),A1(T+2)} in flight.
#define TILE_BODY(t, PB, B0CUR, B0NXT)                                          \
    {                                                                           \
        /* P1 */                                                                \
        READ_B(b1, (PB) + 16384 + 8192);                                        \
        asm volatile("s_waitcnt lgkmcnt(4)" ::: "memory");                      \
        __builtin_amdgcn_sched_barrier(0);                                      \
        if ((t) + 2 < NTILE) STAGE(Abase, (t) + 2, 0, (PB) ? 1 : 0, 0);         \
        __builtin_amdgcn_s_barrier();                                           \
        MFMA16(aA, B0CUR, 0, 0);                                                \
        __builtin_amdgcn_s_barrier();                                           \
        /* P2 */                                                                \
        READ_A(aB, (PB) + 8192);                                                \
        asm volatile("s_waitcnt lgkmcnt(8)" ::: "memory");                      \
        __builtin_amdgcn_sched_barrier(0);                                      \
        if ((t) + 2 < NTILE) STAGE(Bbase, (t) + 2, 0, (PB) ? 1 : 0, 1);         \
        __builtin_amdgcn_s_barrier();                                           \
        MFMA16(aA, b1, 0, 2);                                                   \
        __builtin_amdgcn_s_barrier();                                           \
        /* P3 */                                                                \
        READ_A(aA, (PB) ^ 32768);                                               \
        asm volatile("s_waitcnt lgkmcnt(8)" ::: "memory");                      \
        __builtin_amdgcn_sched_barrier(0);                                      \
        if ((t) + 2 < NTILE) STAGE(Bbase, (t) + 2, 1, (PB) ? 1 : 0, 1);         \
        __builtin_amdgcn_s_barrier();                                           \
        MFMA16(aB, b1, 4, 2);                                                   \
        __builtin_amdgcn_s_barrier();                                           \
        /* P4 */                                                                \
        READ_B(B0NXT, ((PB) ^ 32768) + 16384);                                  \
        asm volatile("s_waitcnt lgkmcnt(4)" ::: "memory");                      \
        __builtin_amdgcn_sched_barrier(0);                                      \
        if ((t) + 2 < NTILE) STAGE(Abase, (t) + 2, 1, (PB) ? 1 : 0, 0);         \
        __builtin_amdgcn_s_barrier();                                           \
        MFMA16(aB, B0CUR, 4, 0);                                                \
        if ((t) < NTILE - 2)       { asm volatile("s_waitcnt vmcnt(4)" ::: "memory"); } \
        else if ((t) == NTILE - 2) { asm volatile("s_waitcnt vmcnt(0)" ::: "memory"); } \
        __builtin_amdgcn_s_barrier();                                           \
    }

__global__ __launch_bounds__(512, 2)
void gemm_8phase(const unsigned short* __restrict__ A,
                 const unsigned short* __restrict__ B,
                 const float* __restrict__ bias,
                 float* __restrict__ out)
{
    __shared__ unsigned short lds[65536];   // 128 KiB: [buf2][op2][half2][8192]

    const int tid  = threadIdx.x;
    const int lane = tid & 63;
    const int wid  = tid >> 6;     // 0..7
    const int wm   = wid >> 2;     // 0..1
    const int wn   = wid & 3;      // 0..3
    const int c15  = lane & 15;
    const int q4   = lane >> 4;
    const int c7   = c15 & 7;

    // 256 blocks = 16x16 output tiles; XCD-bijective swizzle (256 % 8 == 0)
    const int bid = blockIdx.x;
    const int wg  = (bid & 7) * 32 + (bid >> 3);
    const int bm  = wg >> 4;
    const int bn  = wg & 15;

    const unsigned short* Abase = A + (size_t)bm * 64 * 2 * 8192;
    const unsigned short* Bbase = B + (size_t)bn * 64 * 2 * 8192;

    const int stageOff = wid * 1024 + lane * 8;   // elem offset within a 16KB half
    const int rdBase   = c15 * 64;
    const int kcp[2]   = { ((0 + q4) ^ c7) * 8, ((4 + q4) ^ c7) * 8 };

    f32x4 acc[8][4];
    #pragma unroll
    for (int i = 0; i < 8; ++i)
        #pragma unroll
        for (int j = 0; j < 4; ++j)
            acc[i][j] = (f32x4)0.0f;

    bf16x8 aA[4][2];     // A bank alpha (A0 of current tile)
    bf16x8 aB[4][2];     // A bank beta  (A1 of current tile)
    bf16x8 b1[2][2];     // B-half1 of current tile
    bf16x8 b0A[2][2];    // B-half0, even-parity bank
    bf16x8 b0B[2][2];    // B-half0, odd-parity bank

    // prologue: stage tiles 0 and 1 fully, in read-consumption order
    STAGE(Abase, 0, 0, 0, 0);   // A0(0)
    STAGE(Bbase, 0, 0, 0, 1);   // B0(0)
    STAGE(Bbase, 0, 1, 0, 1);   // B1(0)
    STAGE(Abase, 0, 1, 0, 0);   // A1(0)
    STAGE(Abase, 1, 0, 1, 0);   // A0(1)
    STAGE(Bbase, 1, 0, 1, 1);   // B0(1)
    STAGE(Bbase, 1, 1, 1, 1);   // B1(1)
    STAGE(Abase, 1, 1, 1, 0);   // A1(1)
    asm volatile("s_waitcnt vmcnt(4)" ::: "memory");   // leaves {B1(1),A1(1)} in flight
    __builtin_amdgcn_s_barrier();

    // pre-read tile0's P1 operands
    READ_A(aA,  0);          // A0(0)
    READ_B(b0A, 16384);      // B0(0)

    for (int tt = 0; tt < NTILE; tt += 2) {
        TILE_BODY(tt,     0,     b0A, b0B);
        TILE_BODY(tt + 1, 32768, b0B, b0A);
    }

    // Epilogue: bias + maxpool(4 along col) + sum + atomic row add.
    // C/D frag: col = c15, row = q4*4 + r. Wave cols: (nf*4+wn)*16 + c15.
    float rs[8][4];
    #pragma unroll
    for (int mf = 0; mf < 8; ++mf)
        #pragma unroll
        for (int r = 0; r < 4; ++r)
            rs[mf][r] = 0.0f;

    #pragma unroll
    for (int nf = 0; nf < 4; ++nf) {
        const float bv = bias[bn * 256 + (nf * 4 + wn) * 16 + c15];
        #pragma unroll
        for (int mf = 0; mf < 8; ++mf) {
            #pragma unroll
            for (int r = 0; r < 4; ++r) {
                float v = acc[mf][nf][r] + bv;
                v = fmaxf(v, __shfl_xor(v, 1));
                v = fmaxf(v, __shfl_xor(v, 2));
                v += __shfl_xor(v, 4);
                v += __shfl_xor(v, 8);
                rs[mf][r] += v;
            }
        }
    }

    if (c15 == 0) {
        #pragma unroll
        for (int mf = 0; mf < 8; ++mf)
            #pragma unroll
            for (int r = 0; r < 4; ++r) {
                const int row = bm * 256 + (mf * 2 + wm) * 16 + q4 * 4 + r;
                atomicAdd(&out[row], 0.5f * rs[mf][r]);
            }
    }
}

// ---------------- fallback (round-1 kernel, verified) if d_ws too small ----------------
__global__ __launch_bounds__(256, 2)
void fused_gemm_pool_fallback(const float* __restrict__ x,
                              const float* __restrict__ W,
                              const float* __restrict__ b,
                              float* __restrict__ out)
{
    __shared__ unsigned short As[128][72];
    __shared__ unsigned short Bs[128][72];

    const int tid  = threadIdx.x;
    const int lane = tid & 63;
    const int wid  = tid >> 6;
    const int wm   = wid >> 1;
    const int wn   = wid & 1;

    const int bid = blockIdx.x;
    const int wg  = (bid & 7) * 128 + (bid >> 3);
    const int bm  = wg >> 5;
    const int bn  = wg & 31;

    const int srow = tid >> 4;
    const int scol = tid & 15;

    const float* xbase = x + (size_t)(bm * 128 + srow) * KDIM + scol * 4;
    const float* wbase = W + (size_t)(bn * 128 + srow) * KDIM + scol * 4;

    f32x4 acc[4][4];
    #pragma unroll
    for (int i = 0; i < 4; ++i)
        #pragma unroll
        for (int j = 0; j < 4; ++j)
            acc[i][j] = (f32x4)0.0f;

    float4 ra[8], rb[8];
    #pragma unroll
    for (int p = 0; p < 8; ++p) {
        ra[p] = *(const float4*)(xbase + (size_t)(p * 16) * KDIM);
        rb[p] = *(const float4*)(wbase + (size_t)(p * 16) * KDIM);
    }

    for (int kt = 0; kt < KDIM / 64; ++kt) {
        #pragma unroll
        for (int p = 0; p < 8; ++p) {
            const int r = srow + p * 16;
            uint2 pa, pb;
            pa.x = pack_bf16x2(ra[p].x, ra[p].y);
            pa.y = pack_bf16x2(ra[p].z, ra[p].w);
            pb.x = pack_bf16x2(rb[p].x, rb[p].y);
            pb.y = pack_bf16x2(rb[p].z, rb[p].w);
            *(uint2*)&As[r][scol * 4] = pa;
            *(uint2*)&Bs[r][scol * 4] = pb;
        }
        __syncthreads();

        if (kt + 1 < KDIM / 64) {
            const float* xa = xbase + (size_t)(kt + 1) * 64;
            const float* wa = wbase + (size_t)(kt + 1) * 64;
            #pragma unroll
            for (int p = 0; p < 8; ++p) {
                ra[p] = *(const float4*)(xa + (size_t)(p * 16) * KDIM);
                rb[p] = *(const float4*)(wa + (size_t)(p * 16) * KDIM);
            }
        }

        #pragma unroll
        for (int k0 = 0; k0 < 2; ++k0) {
            const int kk = k0 * 32 + (lane >> 4) * 8;
            bf16x8 af[4], bfr[4];
            #pragma unroll
            for (int mf = 0; mf < 4; ++mf)
                af[mf] = *(const bf16x8*)&As[wm * 64 + mf * 16 + (lane & 15)][kk];
            #pragma unroll
            for (int nf = 0; nf < 4; ++nf)
                bfr[nf] = *(const bf16x8*)&Bs[wn * 64 + nf * 16 + (lane & 15)][kk];
            #pragma unroll
            for (int mf = 0; mf < 4; ++mf)
                #pragma unroll
                for (int nf = 0; nf < 4; ++nf)
                    acc[mf][nf] = __builtin_amdgcn_mfma_f32_16x16x32_bf16(
                        af[mf], bfr[nf], acc[mf][nf], 0, 0, 0);
        }
        __syncthreads();
    }

    float rs[4][4];
    #pragma unroll
    for (int mf = 0; mf < 4; ++mf)
        #pragma unroll
        for (int r = 0; r < 4; ++r)
            rs[mf][r] = 0.0f;

    #pragma unroll
    for (int nf = 0; nf < 4; ++nf) {
        const float bv = b[bn * 128 + wn * 64 + nf * 16 + (lane & 15)];
        #pragma unroll
        for (int mf = 0; mf < 4; ++mf) {
            #pragma unroll
            for (int r = 0; r < 4; ++r) {
                float v = acc[mf][nf][r] + bv;
                v = fmaxf(v, __shfl_xor(v, 1));
                v = fmaxf(v, __shfl_xor(v, 2));
                v += __shfl_xor(v, 4);
                v += __shfl_xor(v, 8);
                rs[mf][r] += v;
            }
        }
    }

    if ((lane & 15) == 0) {
        #pragma unroll
        for (int mf = 0; mf < 4; ++mf)
            #pragma unroll
            for (int r = 0; r < 4; ++r) {
                const int row = bm * 128 + wm * 64 + mf * 16 + (lane >> 4) * 4 + r;
                atomicAdd(&out[row], 0.5f * rs[mf][r]);
            }
    }
}

extern "C" void kernel_launch(void* const* d_in, const int* in_sizes, int n_in,
                              void* d_out, int out_size, void* d_ws, size_t ws_size,
                              hipStream_t stream) {
    const float* x = (const float*)d_in[0];
    const float* W = (const float*)d_in[1];
    const float* b = (const float*)d_in[2];
    float* out = (float*)d_out;

    hipMemsetAsync(out, 0, (size_t)out_size * sizeof(float), stream);

    const size_t need = (size_t)NELEM16 * 2 * sizeof(unsigned short); // 64 MB
    if (ws_size >= need) {
        unsigned short* xb = (unsigned short*)d_ws;
        unsigned short* wb = xb + (size_t)NELEM16;
        pack_swz2<<<dim3(2048), dim3(256), 0, stream>>>(x, W, xb, wb);
        gemm_8phase<<<dim3(256), dim3(512), 0, stream>>>(xb, wb, b, out);
    } else {
        fused_gemm_pool_fallback<<<dim3(1024), dim3(256), 0, stream>>>(x, W, b, out);
    }
}

// Round 6
// 163.441 us; speedup vs baseline: 1.1929x; 1.1929x over previous
//
#include <hip/hip_runtime.h>
#include <hip/hip_bf16.h>

#define KDIM 4096
#define NTILE 64                 // K-tiles of 64
#define NELEM16 (1u << 24)       // 4096*4096 elems per matrix

typedef float f32x4 __attribute__((ext_vector_type(4)));
typedef short bf16x8 __attribute__((ext_vector_type(8)));

typedef const __attribute__((address_space(1))) unsigned int g_u32;
typedef __attribute__((address_space(3))) unsigned int l_u32;

__device__ __forceinline__ void gload_lds16(const void* g, void* l) {
    __builtin_amdgcn_global_load_lds((g_u32*)g, (l_u32*)l, 16, 0, 0);
}

__device__ __forceinline__ unsigned int pack_bf16x2(float lo, float hi) {
    __hip_bfloat162 h = __float22bfloat162_rn(float2{lo, hi});
    union { __hip_bfloat162 h; unsigned int u; } c; c.h = h; return c.u;
}

// ---- pack fp32 [4096][4096] -> tiled + XOR-swizzled bf16 staging image ----
__global__ __launch_bounds__(256)
void pack_swz2(const float* __restrict__ x, const float* __restrict__ W,
               unsigned short* __restrict__ xb, unsigned short* __restrict__ wb)
{
    const unsigned int stride = gridDim.x * blockDim.x;
    for (unsigned int i = blockIdx.x * blockDim.x + threadIdx.x; i < (1u << 22); i += stride) {
        const unsigned int j  = i & ((1u << 21) - 1);
        const float* __restrict__ in = (i >> 21) ? W : x;
        unsigned short* __restrict__ out = (i >> 21) ? wb : xb;
        const unsigned int cp = j & 7;
        const unsigned int rl = (j >> 3) & 127;
        const unsigned int c  = cp ^ (rl & 7);
        const unsigned int h  = (j >> 10) & 1;
        const unsigned int kt = (j >> 11) & 63;
        const unsigned int rt = j >> 17;
        const unsigned int row = rt * 256 + h * 128 + rl;
        const unsigned int col = kt * 64 + c * 8;
        const float4* s = (const float4*)(in + (size_t)row * KDIM + col);
        const float4 a = s[0], b = s[1];
        uint4 o;
        o.x = pack_bf16x2(a.x, a.y); o.y = pack_bf16x2(a.z, a.w);
        o.z = pack_bf16x2(b.x, b.y); o.w = pack_bf16x2(b.z, b.w);
        *(uint4*)(out + (size_t)j * 8) = o;
    }
}

// ---- 256x256 GEMM, single-barrier phases, fused bias + maxpool4 + rowsum*0.5 ----
// LDS elem offsets: buf*32768 + op*16384 + half*8192 + rowfrag*1024 + c15*64 + swzchunk*8
#define STAGE(matBase, kt, h, bufn, opIdx)                                      \
    {                                                                           \
        const unsigned short* g_ = (matBase) + ((size_t)(kt) * 2 + (h)) * 8192; \
        const unsigned int lo_ = (bufn) * 32768 + (opIdx) * 16384 + (h) * 8192 + wid * 1024; \
        gload_lds16(g_ + stageOff,       &lds[lo_]);                            \
        gload_lds16(g_ + stageOff + 512, &lds[lo_ + 512]);                      \
    }

#define READ_A(dst, base)                                                       \
    _Pragma("unroll") for (int m = 0; m < 4; ++m)                               \
      _Pragma("unroll") for (int k = 0; k < 2; ++k)                             \
        dst[m][k] = *(const bf16x8*)&lds[(base) + (m * 2 + wm) * 1024 + rdBase + kcp[k]];

#define READ_B(dst, base)                                                       \
    _Pragma("unroll") for (int n = 0; n < 2; ++n)                               \
      _Pragma("unroll") for (int k = 0; k < 2; ++k)                             \
        dst[n][k] = *(const bf16x8*)&lds[(base) + (n * 4 + wn) * 1024 + rdBase + kcp[k]];

#define MFMA16(AF, BF, MO, NO)                                                  \
    __builtin_amdgcn_s_setprio(1);                                              \
    _Pragma("unroll") for (int m = 0; m < 4; ++m)                               \
      _Pragma("unroll") for (int n = 0; n < 2; ++n)                             \
        _Pragma("unroll") for (int k = 0; k < 2; ++k)                           \
          acc[(MO) + m][(NO) + n] = __builtin_amdgcn_mfma_f32_16x16x32_bf16(    \
              AF[m][k], BF[n][k], acc[(MO) + m][(NO) + n], 0, 0, 0);            \
    __builtin_amdgcn_s_setprio(0);

#define SYNCPT()                                                                \
    asm volatile("s_waitcnt vmcnt(4)" ::: "memory");                            \
    __builtin_amdgcn_s_barrier();                                               \
    __builtin_amdgcn_sched_barrier(0);

// Per tile T (buf parity base PB): phase layout [reads; stage; vmcnt(4); BAR; MFMA].
// Quads: P1:(A0,B0) P2:(A0,B1) P3:(A1,B1) P4:(A1,B0). Reads feed SAME-phase MFMA
// (min register liveness: afr reused for A0/A1, b0 lives whole tile, b1 P2-P3).
// Stages (all tile T+1 -> other buf): P1:A0 P2:B0 P3:B1 P4:A1.
//   WAR: each staged region's last read is 4-5 phases earlier (>= 2 needed).
//   RAW: per-wave vmcnt(4) drains a stage 2 phases after issue; cross-wave via the
//        barrier chain (drain phase <= reader's preceding barrier for all regions).
// Single barrier per phase: a wave finishing MFMA(j) early issues reads(j+1)
// immediately, so LDS-read service overlaps laggard waves' MFMA clusters.
#define TILE_BODY(t, PB, BUFN)                                                  \
    {                                                                           \
        /* P1 */                                                                \
        READ_A(afr, (PB));                                                      \
        READ_B(b0, (PB) + 16384);                                               \
        if ((t) + 1 < NTILE) STAGE(Abase, (t) + 1, 0, BUFN, 0);                 \
        SYNCPT();                                                               \
        MFMA16(afr, b0, 0, 0);                                                  \
        /* P2 */                                                                \
        READ_B(b1, (PB) + 16384 + 8192);                                        \
        if ((t) + 1 < NTILE) STAGE(Bbase, (t) + 1, 0, BUFN, 1);                 \
        SYNCPT();                                                               \
        MFMA16(afr, b1, 0, 2);                                                  \
        /* P3 */                                                                \
        READ_A(afr, (PB) + 8192);                                               \
        if ((t) + 1 < NTILE) STAGE(Bbase, (t) + 1, 1, BUFN, 1);                 \
        SYNCPT();                                                               \
        MFMA16(afr, b1, 4, 2);                                                  \
        /* P4 */                                                                \
        if ((t) + 1 < NTILE) STAGE(Abase, (t) + 1, 1, BUFN, 0);                 \
        SYNCPT();                                                               \
        MFMA16(afr, b0, 4, 0);                                                  \
    }

__global__ __launch_bounds__(512, 2)
void gemm_8phase(const unsigned short* __restrict__ A,
                 const unsigned short* __restrict__ B,
                 const float* __restrict__ bias,
                 float* __restrict__ out)
{
    __shared__ unsigned short lds[65536];   // 128 KiB: [buf2][op2][half2][8192]

    const int tid  = threadIdx.x;
    const int lane = tid & 63;
    const int wid  = tid >> 6;     // 0..7
    const int wm   = wid >> 2;     // 0..1
    const int wn   = wid & 3;      // 0..3
    const int c15  = lane & 15;
    const int q4   = lane >> 4;
    const int c7   = c15 & 7;

    // 256 blocks = 16x16 output tiles; XCD-bijective swizzle (256 % 8 == 0)
    const int bid = blockIdx.x;
    const int wg  = (bid & 7) * 32 + (bid >> 3);
    const int bm  = wg >> 4;
    const int bn  = wg & 15;

    const unsigned short* Abase = A + (size_t)bm * 64 * 2 * 8192;
    const unsigned short* Bbase = B + (size_t)bn * 64 * 2 * 8192;

    const int stageOff = wid * 1024 + lane * 8;   // elem offset within a 16KB half
    const int rdBase   = c15 * 64;
    const int kcp[2]   = { ((0 + q4) ^ c7) * 8, ((4 + q4) ^ c7) * 8 };

    f32x4 acc[8][4];
    #pragma unroll
    for (int i = 0; i < 8; ++i)
        #pragma unroll
        for (int j = 0; j < 4; ++j)
            acc[i][j] = (f32x4)0.0f;

    bf16x8 afr[4][2];    // A fragments (A0 in P1-P2, A1 in P3-P4)
    bf16x8 b0[2][2];     // B-half0 (live whole tile)
    bf16x8 b1[2][2];     // B-half1 (live P2-P3)

    // prologue: stage tile0 -> buf0 in read-consumption order; tile0's body stages tile1
    STAGE(Abase, 0, 0, 0, 0);   // A0(0)
    STAGE(Bbase, 0, 0, 0, 1);   // B0(0)
    STAGE(Bbase, 0, 1, 0, 1);   // B1(0)
    STAGE(Abase, 0, 1, 0, 0);   // A1(0)
    asm volatile("s_waitcnt vmcnt(4)" ::: "memory");   // A0,B0 landed; B1,A1 in flight
    __builtin_amdgcn_s_barrier();
    __builtin_amdgcn_sched_barrier(0);

    for (int tt = 0; tt < NTILE; tt += 2) {
        TILE_BODY(tt,     0,     1);
        TILE_BODY(tt + 1, 32768, 0);
    }

    // Epilogue: bias + maxpool(4 along col) + sum + atomic row add.
    // C/D frag: col = c15, row = q4*4 + r. Wave cols: (nf*4+wn)*16 + c15.
    float rs[8][4];
    #pragma unroll
    for (int mf = 0; mf < 8; ++mf)
        #pragma unroll
        for (int r = 0; r < 4; ++r)
            rs[mf][r] = 0.0f;

    #pragma unroll
    for (int nf = 0; nf < 4; ++nf) {
        const float bv = bias[bn * 256 + (nf * 4 + wn) * 16 + c15];
        #pragma unroll
        for (int mf = 0; mf < 8; ++mf) {
            #pragma unroll
            for (int r = 0; r < 4; ++r) {
                float v = acc[mf][nf][r] + bv;
                v = fmaxf(v, __shfl_xor(v, 1));
                v = fmaxf(v, __shfl_xor(v, 2));
                v += __shfl_xor(v, 4);
                v += __shfl_xor(v, 8);
                rs[mf][r] += v;
            }
        }
    }

    if (c15 == 0) {
        #pragma unroll
        for (int mf = 0; mf < 8; ++mf)
            #pragma unroll
            for (int r = 0; r < 4; ++r) {
                const int row = bm * 256 + (mf * 2 + wm) * 16 + q4 * 4 + r;
                atomicAdd(&out[row], 0.5f * rs[mf][r]);
            }
    }
}

// ---------------- fallback (round-1 kernel, verified) if d_ws too small ----------------
__global__ __launch_bounds__(256, 2)
void fused_gemm_pool_fallback(const float* __restrict__ x,
                              const float* __restrict__ W,
                              const float* __restrict__ b,
                              float* __restrict__ out)
{
    __shared__ unsigned short As[128][72];
    __shared__ unsigned short Bs[128][72];

    const int tid  = threadIdx.x;
    const int lane = tid & 63;
    const int wid  = tid >> 6;
    const int wm   = wid >> 1;
    const int wn   = wid & 1;

    const int bid = blockIdx.x;
    const int wg  = (bid & 7) * 128 + (bid >> 3);
    const int bm  = wg >> 5;
    const int bn  = wg & 31;

    const int srow = tid >> 4;
    const int scol = tid & 15;

    const float* xbase = x + (size_t)(bm * 128 + srow) * KDIM + scol * 4;
    const float* wbase = W + (size_t)(bn * 128 + srow) * KDIM + scol * 4;

    f32x4 acc[4][4];
    #pragma unroll
    for (int i = 0; i < 4; ++i)
        #pragma unroll
        for (int j = 0; j < 4; ++j)
            acc[i][j] = (f32x4)0.0f;

    float4 ra[8], rb[8];
    #pragma unroll
    for (int p = 0; p < 8; ++p) {
        ra[p] = *(const float4*)(xbase + (size_t)(p * 16) * KDIM);
        rb[p] = *(const float4*)(wbase + (size_t)(p * 16) * KDIM);
    }

    for (int kt = 0; kt < KDIM / 64; ++kt) {
        #pragma unroll
        for (int p = 0; p < 8; ++p) {
            const int r = srow + p * 16;
            uint2 pa, pb;
            pa.x = pack_bf16x2(ra[p].x, ra[p].y);
            pa.y = pack_bf16x2(ra[p].z, ra[p].w);
            pb.x = pack_bf16x2(rb[p].x, rb[p].y);
            pb.y = pack_bf16x2(rb[p].z, rb[p].w);
            *(uint2*)&As[r][scol * 4] = pa;
            *(uint2*)&Bs[r][scol * 4] = pb;
        }
        __syncthreads();

        if (kt + 1 < KDIM / 64) {
            const float* xa = xbase + (size_t)(kt + 1) * 64;
            const float* wa = wbase + (size_t)(kt + 1) * 64;
            #pragma unroll
            for (int p = 0; p < 8; ++p) {
                ra[p] = *(const float4*)(xa + (size_t)(p * 16) * KDIM);
                rb[p] = *(const float4*)(wa + (size_t)(p * 16) * KDIM);
            }
        }

        #pragma unroll
        for (int k0 = 0; k0 < 2; ++k0) {
            const int kk = k0 * 32 + (lane >> 4) * 8;
            bf16x8 af[4], bfr[4];
            #pragma unroll
            for (int mf = 0; mf < 4; ++mf)
                af[mf] = *(const bf16x8*)&As[wm * 64 + mf * 16 + (lane & 15)][kk];
            #pragma unroll
            for (int nf = 0; nf < 4; ++nf)
                bfr[nf] = *(const bf16x8*)&Bs[wn * 64 + nf * 16 + (lane & 15)][kk];
            #pragma unroll
            for (int mf = 0; mf < 4; ++mf)
                #pragma unroll
                for (int nf = 0; nf < 4; ++nf)
                    acc[mf][nf] = __builtin_amdgcn_mfma_f32_16x16x32_bf16(
                        af[mf], bfr[nf], acc[mf][nf], 0, 0, 0);
        }
        __syncthreads();
    }

    float rs[4][4];
    #pragma unroll
    for (int mf = 0; mf < 4; ++mf)
        #pragma unroll
        for (int r = 0; r < 4; ++r)
            rs[mf][r] = 0.0f;

    #pragma unroll
    for (int nf = 0; nf < 4; ++nf) {
        const float bv = b[bn * 128 + wn * 64 + nf * 16 + (lane & 15)];
        #pragma unroll
        for (int mf = 0; mf < 4; ++mf) {
            #pragma unroll
            for (int r = 0; r < 4; ++r) {
                float v = acc[mf][nf][r] + bv;
                v = fmaxf(v, __shfl_xor(v, 1));
                v = fmaxf(v, __shfl_xor(v, 2));
                v += __shfl_xor(v, 4);
                v += __shfl_xor(v, 8);
                rs[mf][r] += v;
            }
        }
    }

    if ((lane & 15) == 0) {
        #pragma unroll
        for (int mf = 0; mf < 4; ++mf)
            #pragma unroll
            for (int r = 0; r < 4; ++r) {
                const int row = bm * 128 + wm * 64 + mf * 16 + (lane >> 4) * 4 + r;
                atomicAdd(&out[row], 0.5f * rs[mf][r]);
            }
    }
}

extern "C" void kernel_launch(void* const* d_in, const int* in_sizes, int n_in,
                              void* d_out, int out_size, void* d_ws, size_t ws_size,
                              hipStream_t stream) {
    const float* x = (const float*)d_in[0];
    const float* W = (const float*)d_in[1];
    const float* b = (const float*)d_in[2];
    float* out = (float*)d_out;

    hipMemsetAsync(out, 0, (size_t)out_size * sizeof(float), stream);

    const size_t need = (size_t)NELEM16 * 2 * sizeof(unsigned short); // 64 MB
    if (ws_size >= need) {
        unsigned short* xb = (unsigned short*)d_ws;
        unsigned short* wb = xb + (size_t)NELEM16;
        pack_swz2<<<dim3(2048), dim3(256), 0, stream>>>(x, W, xb, wb);
        gemm_8phase<<<dim3(256), dim3(512), 0, stream>>>(xb, wb, b, out);
    } else {
        fused_gemm_pool_fallback<<<dim3(1024), dim3(256), 0, stream>>>(x, W, b, out);
    }
}